// Round 2
// baseline (3318.322 us; speedup 1.0000x reference)
//
#include <hip/hip_runtime.h>

#define NN 1024
#define NOPEN 128
#define NHID 256
#define NSTART 40
#define NCLOSE 3
#define NLAYERS 40
#define KSZ 9

static constexpr float H2 = 0.01f;     // h*h, h = 0.1
static constexpr float IN_EPS = 1e-5f; // instance norm eps

using floatx4 = __attribute__((ext_vector_type(4))) float;
using bfrag = __attribute__((ext_vector_type(8))) short; // 8 bf16 = 4 VGPRs

__device__ __forceinline__ ushort f2bf(float f) {
    union { float f; unsigned u; } v; v.f = f;
    unsigned r = v.u + 0x7fffu + ((v.u >> 16) & 1u); // RNE
    return (ushort)(r >> 16);
}

// weight prep in MFMA-fragment-major order:
// Wf1: conv A-frags:  frag index ((z*9+t)*16 + g)*4 + kc   (g = co-tile of 16, kc = k-quad of 32)
// Wf2: convT A-frags: frag index ((z*9+t)*8 + g)*8 + j     (g = ci-tile of 16, j = k-oct of 32)
// each frag = 512 ushorts = 1KB (64 lanes x 16B), one coalesced dwordx4 per wave.
__device__ __forceinline__ void prepw_piece(const float* __restrict__ W, ushort* __restrict__ Wf1,
                                            ushort* __restrict__ Wf2, int lb, int lsrc, int tid) {
    if (lb < 72) {
        int z = lb / 36, rem = lb % 36;
        int t = rem >> 2, q = rem & 3;
        const float* Wz = W + (size_t)(lsrc * 2 + z) * (NHID * NOPEN * KSZ);
        ushort* dst = Wf1 + (((size_t)(z * 9 + t) * 64 + q * 16) << 9);
#pragma unroll
        for (int r = 0; r < 32; ++r) {
            int ei = r * 256 + tid;
            int g = q * 4 + (ei >> 11);
            int kc = (ei >> 9) & 3;
            int lm = (ei >> 3) & 15, lq = (ei >> 7) & 3;
            int e = ei & 7;
            int co = g * 16 + lm, ci = kc * 32 + lq * 8 + e;
            dst[ei] = f2bf(Wz[co * (NOPEN * KSZ) + ci * KSZ + t]);
        }
    } else {
        int p2 = lb - 72;
        int z = p2 / 36, rem = p2 % 36;
        int t = rem >> 2, q = rem & 3;
        const float* Wz = W + (size_t)(lsrc * 2 + z) * (NHID * NOPEN * KSZ);
        ushort* dst = Wf2 + (((size_t)(z * 9 + t) * 64 + q * 16) << 9);
#pragma unroll
        for (int r = 0; r < 32; ++r) {
            int ei = r * 256 + tid;
            int fb = q * 16 + (ei >> 9);
            int g = fb >> 3, j = fb & 7;
            int lm = (ei >> 3) & 15, lq = (ei >> 7) & 3;
            int e = ei & 7;
            int ci = g * 16 + lm, co = j * 32 + lq * 8 + e;
            dst[ei] = f2bf(Wz[co * (NOPEN * KSZ) + ci * KSZ + t]);
        }
    }
}

// ---------------- opening: Zc/Zold/Zct(layer0) + weight prep(layer0) + pads + sig=0 + Stats=0 ----------------
__global__ __launch_bounds__(256) void k_open(const float* __restrict__ Kopen, const float* __restrict__ Z,
                       float* __restrict__ Zc, float* __restrict__ Zold,
                       const float* __restrict__ Bias0, ushort* __restrict__ Zct,
                       const float* __restrict__ W, ushort* __restrict__ Wf1,
                       ushort* __restrict__ Wf2, float* __restrict__ sig, float* __restrict__ Stats) {
    const int v = blockIdx.x, tid = threadIdx.x;
    if (v < 512) {
        int o = v >> 2, n = (v & 3) * 256 + tid;
        float acc = 0.f;
#pragma unroll
        for (int s = 0; s < NSTART; ++s)
            acc = fmaf(Kopen[o * NSTART + s], Z[s * NN + n], acc);
        Zc[o * NN + n] = acc;
        Zold[o * NN + n] = acc;
#pragma unroll
        for (int z = 0; z < 2; ++z)
            Zct[z * (1032 * 128) + (n + 4) * 128 + o] = f2bf(acc + Bias0[z * NOPEN + o]);
    } else if (v < 656) {
        prepw_piece(W, Wf1, Wf2, v - 512, 0, tid);
    } else {
        if (tid == 0) sig[0] = 0.f;
        for (int idx = tid; idx < 1024; idx += 256) Stats[idx] = 0.f;
        for (int idx = tid; idx < 1024; idx += 256) {
            int z = idx >> 9, rr = idx & 511;
            ushort* Zz = Zct + z * (1032 * 128);
            Zz[rr] = 0; Zz[1028 * 128 + rr] = 0;
        }
    }
}

// ---------------- D2 = max(sq_i + sq_j - 2 Z^T Z, 0); sum(D2) -> sig ----------------
__global__ __launch_bounds__(256) void k_d2(const float* __restrict__ Zc,
                                            float* __restrict__ D2, float* __restrict__ sig) {
    __shared__ __align__(16) float Zi[32 * 36];
    __shared__ __align__(16) float Zj[32 * 68];
    __shared__ float sqi[32], sqj[64];
    __shared__ float red[4];
    const int tid = threadIdx.x;
    const int tx = tid & 15, ty = tid >> 4;
    const int j0 = blockIdx.x * 64, i0 = blockIdx.y * 32;
    if (tid < 32) sqi[tid] = 0.f;
    else if (tid < 96) sqj[tid - 32] = 0.f;
    float acc[2][4] = {};
    for (int c0 = 0; c0 < NOPEN; c0 += 32) {
        for (int idx = tid; idx < 32 * 32; idx += 256) {
            int c = idx >> 5, ii = idx & 31;
            Zi[c * 36 + ii] = Zc[(c0 + c) * NN + i0 + ii];
        }
        for (int idx = tid; idx < 32 * 64; idx += 256) {
            int c = idx >> 6, jj = idx & 63;
            Zj[c * 68 + jj] = Zc[(c0 + c) * NN + j0 + jj];
        }
        __syncthreads();
        if (tid < 32) {
            float s = 0.f;
            for (int c = 0; c < 32; ++c) { float x = Zi[c * 36 + tid]; s = fmaf(x, x, s); }
            sqi[tid] += s;
        } else if (tid < 96) {
            int jj = tid - 32;
            float s = 0.f;
            for (int c = 0; c < 32; ++c) { float x = Zj[c * 68 + jj]; s = fmaf(x, x, s); }
            sqj[jj] += s;
        }
#pragma unroll 8
        for (int c = 0; c < 32; ++c) {
            float2 zi = *(const float2*)&Zi[c * 36 + ty * 2];
            float4 zj = *(const float4*)&Zj[c * 68 + tx * 4];
            acc[0][0] = fmaf(zi.x, zj.x, acc[0][0]);
            acc[0][1] = fmaf(zi.x, zj.y, acc[0][1]);
            acc[0][2] = fmaf(zi.x, zj.z, acc[0][2]);
            acc[0][3] = fmaf(zi.x, zj.w, acc[0][3]);
            acc[1][0] = fmaf(zi.y, zj.x, acc[1][0]);
            acc[1][1] = fmaf(zi.y, zj.y, acc[1][1]);
            acc[1][2] = fmaf(zi.y, zj.z, acc[1][2]);
            acc[1][3] = fmaf(zi.y, zj.w, acc[1][3]);
        }
        __syncthreads();
    }
    float part = 0.f;
#pragma unroll
    for (int m = 0; m < 2; ++m) {
        int i = i0 + ty * 2 + m;
        float sqi_v = sqi[ty * 2 + m];
        float4 d;
        d.x = fmaxf(sqi_v + sqj[tx * 4 + 0] - 2.f * acc[m][0], 0.f);
        d.y = fmaxf(sqi_v + sqj[tx * 4 + 1] - 2.f * acc[m][1], 0.f);
        d.z = fmaxf(sqi_v + sqj[tx * 4 + 2] - 2.f * acc[m][2], 0.f);
        d.w = fmaxf(sqi_v + sqj[tx * 4 + 3] - 2.f * acc[m][3], 0.f);
        *(float4*)&D2[(size_t)i * NN + j0 + tx * 4] = d;
        part += (d.x + d.y) + (d.z + d.w);
    }
#pragma unroll
    for (int off = 32; off > 0; off >>= 1) part += __shfl_down(part, off);
    if ((tid & 63) == 0) red[tid >> 6] = part;
    __syncthreads();
    if (tid == 0) atomicAdd(sig, red[0] + red[1] + red[2] + red[3]);
}

// ---------------- deg_i = sum_j exp(-D2_ij/sigma); Dh_i = rsqrt(deg_i) ----------------
__global__ void k_deg(const float* __restrict__ D2, const float* __restrict__ sig,
                      float* __restrict__ Dh) {
    __shared__ float red[4];
    int i = blockIdx.x, tid = threadIdx.x;
    float inv = 1.f / (sig[0] * (1.f / 1048576.f) + 1e-12f);
    float4 v = *(const float4*)&D2[(size_t)i * NN + tid * 4];
    float s = __expf(-v.x * inv) + __expf(-v.y * inv) + __expf(-v.z * inv) + __expf(-v.w * inv);
#pragma unroll
    for (int off = 32; off > 0; off >>= 1) s += __shfl_down(s, off);
    if ((tid & 63) == 0) red[tid >> 6] = s;
    __syncthreads();
    if (tid == 0) Dh[i] = rsqrtf(red[0] + red[1] + red[2] + red[3]);
}

// ---------------- Lb_ij = bf16( delta_ij - Dh_i Dh_j exp(-D2_ij/sigma) ) ----------------
__global__ void k_L(const float* __restrict__ D2, const float* __restrict__ sig,
                    const float* __restrict__ Dh, ushort* __restrict__ Lb) {
    int i = blockIdx.x, tid = threadIdx.x;
    int j = tid * 4;
    float inv = 1.f / (sig[0] * (1.f / 1048576.f) + 1e-12f);
    float dhi = Dh[i];
    float4 v = *(const float4*)&D2[(size_t)i * NN + j];
    float4 dj = *(const float4*)&Dh[j];
    float4 o;
    o.x = -dhi * dj.x * __expf(-v.x * inv);
    o.y = -dhi * dj.y * __expf(-v.y * inv);
    o.z = -dhi * dj.z * __expf(-v.z * inv);
    o.w = -dhi * dj.w * __expf(-v.w * inv);
    if (i == j + 0) o.x += 1.f;
    if (i == j + 1) o.y += 1.f;
    if (i == j + 2) o.z += 1.f;
    if (i == j + 3) o.w += 1.f;
    ushort4 ob; ob.x = f2bf(o.x); ob.y = f2bf(o.y); ob.z = f2bf(o.z); ob.w = f2bf(o.w);
    *(ushort4*)&Lb[(size_t)i * NN + j] = ob;
}

// ---------------- MFMA conv1d + fused C0 stats: C[co,p] = sum_{t,ci} W[t][co][ci]*Zct[p+t][ci] ----------------
// grid (16 p, 8 co, 2 z); z=0 blocks atomically accumulate per-channel sum/sumsq into Stats[0/256]
__global__ __launch_bounds__(256) void k_conv(const ushort* __restrict__ Zct,
        const ushort* __restrict__ Wf1, float* __restrict__ C0, ushort* __restrict__ C1b,
        float* __restrict__ Stats) {
    const int z = blockIdx.z;
    const int p0 = blockIdx.x * 64, co0 = blockIdx.y * 32;
    __shared__ ushort Xs[72 * 136];
    const int tid = threadIdx.x;
    const ushort* Zz = Zct + z * (1032 * 128);
    for (int idx = tid; idx < 1152; idx += 256) {
        int row = idx >> 4, ch = (idx & 15) * 8;
        *(bfrag*)&Xs[row * 136 + ch] = *(const bfrag*)&Zz[(p0 + row) * 128 + ch];
    }
    __syncthreads();
    const int l = tid & 63, wv = tid >> 6;
    const int wm = wv >> 1, wn = wv & 1;
    const int lm = l & 15, lq = l >> 4;
    const ushort* wf = Wf1 + (((size_t)z * 144 + (blockIdx.y * 2 + wm)) << 11) + l * 8;
    floatx4 acc[2] = {};
    bfrag a_cur[4];
#pragma unroll
    for (int kc = 0; kc < 4; ++kc) a_cur[kc] = *(const bfrag*)(wf + (kc << 9));
    for (int t = 0; t < 9; ++t) {
        bfrag a_nxt[4];
        if (t < 8) {
            const ushort* wptr = wf + (size_t)(t + 1) * (16 << 11);
#pragma unroll
            for (int kc = 0; kc < 4; ++kc) a_nxt[kc] = *(const bfrag*)(wptr + (kc << 9));
        }
        const int xbase = (wn * 32 + lm + t) * 136 + lq * 8;
#pragma unroll
        for (int kc = 0; kc < 4; ++kc) {
            bfrag b0 = *(const bfrag*)&Xs[xbase + kc * 32];
            acc[0] = __builtin_amdgcn_mfma_f32_16x16x32_bf16(a_cur[kc], b0, acc[0], 0, 0, 0);
            bfrag b1 = *(const bfrag*)&Xs[xbase + 16 * 136 + kc * 32];
            acc[1] = __builtin_amdgcn_mfma_f32_16x16x32_bf16(a_cur[kc], b1, acc[1], 0, 0, 0);
        }
#pragma unroll
        for (int kc = 0; kc < 4; ++kc) a_cur[kc] = a_nxt[kc];
    }
    const int cog = co0 + wm * 16 + lq * 4;
    const int pg = p0 + wn * 32 + lm;
#pragma unroll
    for (int j = 0; j < 2; ++j)
#pragma unroll
        for (int r = 0; r < 4; ++r) {
            if (z == 0) C0[(cog + r) * NN + pg + j * 16] = acc[j][r];
            else        C1b[(cog + r) * NN + pg + j * 16] = f2bf(acc[j][r]);
        }
    if (z == 0) {
        float s[4], q2[4];
#pragma unroll
        for (int r = 0; r < 4; ++r) {
            s[r] = acc[0][r] + acc[1][r];
            q2[r] = acc[0][r] * acc[0][r] + acc[1][r] * acc[1][r];
        }
#pragma unroll
        for (int off = 1; off < 16; off <<= 1)
#pragma unroll
            for (int r = 0; r < 4; ++r) {
                s[r] += __shfl_xor(s[r], off);
                q2[r] += __shfl_xor(q2[r], off);
            }
        if (lm == 0)
#pragma unroll
            for (int r = 0; r < 4; ++r) {
                atomicAdd(&Stats[cog + r], s[r]);
                atomicAdd(&Stats[256 + cog + r], q2[r]);
            }
    }
}

// ---------------- full-K MFMA GEMM: A1 = C1b @ L, fused per-channel stats -> Stats[512/768] ----------------
// grid (8 nt of 128, 8 mt of 32); K = 1024 looped; plain stores, no pre-zero needed
__global__ __launch_bounds__(256) void k_xl1(const ushort* __restrict__ X,
                                             const ushort* __restrict__ Lb,
                                             float* __restrict__ A1, float* __restrict__ Stats) {
    __shared__ __align__(16) ushort As[32 * 136];
    __shared__ __align__(16) ushort Bs[128 * 136];
    const int tid = threadIdx.x;
    const int lane = tid & 63, wave = tid >> 6;
    const int wm = wave >> 1, wn = wave & 1;
    const int lm = lane & 15, lq = lane >> 4;
    const int n0 = blockIdx.x * 128, m0 = blockIdx.y * 32;
    floatx4 acc[4] = {};
    for (int kc = 0; kc < 1024; kc += 128) {
        __syncthreads();
        {
            int q = tid;
#pragma unroll
            for (int r = 0; r < 2; ++r, q += 256) {
                int row = q >> 4, ch = (q & 15) * 8;
                *(bfrag*)&As[row * 136 + ch] = *(const bfrag*)&X[(m0 + row) * NN + kc + ch];
            }
            q = tid;
#pragma unroll
            for (int r = 0; r < 8; ++r, q += 256) {
                int row = q >> 4, ch = (q & 15) * 8;
                *(bfrag*)&Bs[row * 136 + ch] = *(const bfrag*)&Lb[(n0 + row) * NN + kc + ch];
            }
        }
        __syncthreads();
#pragma unroll
        for (int ks = 0; ks < 4; ++ks) {
            bfrag a = *(const bfrag*)&As[(wm * 16 + lm) * 136 + ks * 32 + lq * 8];
#pragma unroll
            for (int j = 0; j < 4; ++j) {
                bfrag b = *(const bfrag*)&Bs[(wn * 64 + j * 16 + lm) * 136 + ks * 32 + lq * 8];
                acc[j] = __builtin_amdgcn_mfma_f32_16x16x32_bf16(a, b, acc[j], 0, 0, 0);
            }
        }
    }
    const int mg0 = m0 + wm * 16 + lq * 4;
    const int ng0 = n0 + wn * 64 + lm;
#pragma unroll
    for (int j = 0; j < 4; ++j)
#pragma unroll
        for (int r = 0; r < 4; ++r)
            A1[(size_t)(mg0 + r) * NN + ng0 + j * 16] = acc[j][r];
    // per-channel partial sums over this block's 64-n strip (final values -> stats are exact)
    float s[4], q2[4];
#pragma unroll
    for (int r = 0; r < 4; ++r) {
        s[r] = (acc[0][r] + acc[1][r]) + (acc[2][r] + acc[3][r]);
        q2[r] = (acc[0][r] * acc[0][r] + acc[1][r] * acc[1][r]) +
                (acc[2][r] * acc[2][r] + acc[3][r] * acc[3][r]);
    }
#pragma unroll
    for (int off = 1; off < 16; off <<= 1)
#pragma unroll
        for (int r = 0; r < 4; ++r) {
            s[r] += __shfl_xor(s[r], off);
            q2[r] += __shfl_xor(q2[r], off);
        }
    if (lm == 0)
#pragma unroll
        for (int r = 0; r < 4; ++r) {
            atomicAdd(&Stats[512 + mg0 + r], s[r]);
            atomicAdd(&Stats[768 + mg0 + r], q2[r]);
        }
}

// ---------------- fused instance-norm + relu + transpose + MFMA convT ----------------
// grid (16 p, 2 cihalf, 2 z). Each block normalizes its own 72-row halo window (thread=channel,
// stats read from Stats, no extra barrier), stages transposed bf16 in LDS, then convT MFMAs.
__global__ __launch_bounds__(256) void k_nct(const float* __restrict__ C0, const float* __restrict__ A1,
        const float* __restrict__ Stats, const ushort* __restrict__ Wf2,
        float* __restrict__ Tacc, ushort* __restrict__ T1b) {
    const int z = blockIdx.z;
    const int cih = blockIdx.y;
    const int p0 = blockIdx.x * 64;
    __shared__ ushort Al[72 * 264];
    const int tid = threadIdx.x;
    const float* in = z ? A1 : C0;
    {
        const int co = tid; // 256 threads = 256 channels
        float S = Stats[z * 512 + co], Q = Stats[z * 512 + 256 + co];
        float mean = S * (1.f / NN);
        float var = Q * (1.f / NN) - mean * mean;
        float rs = rsqrtf(var + IN_EPS);
        const float* row = in + (size_t)co * NN;
#pragma unroll
        for (int k = 0; k < 18; ++k) {
            int p = p0 - 4 + k * 4;
            float4 v;
            if ((unsigned)p < 1024u) v = *(const float4*)&row[p];
            else { v.x = v.y = v.z = v.w = 0.f; }
            Al[(k * 4 + 0) * 264 + co] = f2bf(fmaxf((v.x - mean) * rs, 0.f));
            Al[(k * 4 + 1) * 264 + co] = f2bf(fmaxf((v.y - mean) * rs, 0.f));
            Al[(k * 4 + 2) * 264 + co] = f2bf(fmaxf((v.z - mean) * rs, 0.f));
            Al[(k * 4 + 3) * 264 + co] = f2bf(fmaxf((v.w - mean) * rs, 0.f));
        }
    }
    __syncthreads();
    const int l = tid & 63, wv = tid >> 6;
    const int lm = l & 15, lq = l >> 4;
    floatx4 acc[4] = {};
    const ushort* wz = Wf2 + (((size_t)z * 72 + cih * 4) << 12) + l * 8;
    for (int t = 0; t < 9; ++t) {
        const int abase = (wv * 16 + lm + 8 - t) * 264 + lq * 8;
        const ushort* wt = wz + (size_t)t * (8 << 12);
#pragma unroll
        for (int j = 0; j < 8; ++j) {
            bfrag b = *(const bfrag*)&Al[abase + j * 32];
#pragma unroll
            for (int sub = 0; sub < 4; ++sub) {
                bfrag a = *(const bfrag*)(wt + ((size_t)sub << 12) + (j << 9));
                acc[sub] = __builtin_amdgcn_mfma_f32_16x16x32_bf16(a, b, acc[sub], 0, 0, 0);
            }
        }
    }
    const int pg = p0 + wv * 16 + lm;
#pragma unroll
    for (int sub = 0; sub < 4; ++sub) {
        int cig = cih * 64 + sub * 16 + lq * 4;
#pragma unroll
        for (int r = 0; r < 4; ++r) {
            if (z == 0) Tacc[(cig + r) * NN + pg] = acc[sub][r];
            else        T1b[(cig + r) * NN + pg] = f2bf(acc[sub][r]);
        }
    }
}

// ---------------- full-K XL2 + fused leapfrog + Zct production + prepw + zeroing ----------------
// grid 273: b<128 GEMM tiles (16 nt of 64 x 8 mt of 16), b in [128,272) prepw, b==272 zero sig/Stats
__global__ __launch_bounds__(256) void k_xl2leap(const ushort* __restrict__ T1b,
        const ushort* __restrict__ Lb, const float* __restrict__ Tacc,
        const float* __restrict__ Zc, float* __restrict__ Zo,
        const float* __restrict__ BiasN, ushort* __restrict__ Zct,
        const float* __restrict__ W, ushort* __restrict__ Wf1, ushort* __restrict__ Wf2,
        float* __restrict__ Stats, float* __restrict__ sig, int lnext, int doprep) {
    const int b = blockIdx.x, tid = threadIdx.x;
    __shared__ __align__(16) ushort As[16 * 136];
    __shared__ __align__(16) ushort Bs[64 * 136];
    __shared__ __align__(16) ushort Zt[2 * 64 * 16];
    if (b >= 128) {
        if (b < 272) {
            if (doprep) prepw_piece(W, Wf1, Wf2, b - 128, lnext, tid);
        } else {
            if (tid == 0) sig[0] = 0.f;
            float4 z4 = {0.f, 0.f, 0.f, 0.f};
            *(float4*)&Stats[tid * 4] = z4;
        }
        return;
    }
    const int nt = b >> 3, mt = b & 7;
    const int n0 = nt * 64, m0 = mt * 16;
    const int lane = tid & 63, wv = tid >> 6;
    const int lm = lane & 15, lq = lane >> 4;
    floatx4 acc = {};
    for (int kc = 0; kc < 1024; kc += 128) {
        __syncthreads();
        {
            int row = tid >> 4, ch = (tid & 15) * 8;
            *(bfrag*)&As[row * 136 + ch] = *(const bfrag*)&T1b[(m0 + row) * NN + kc + ch];
#pragma unroll
            for (int r = 0; r < 4; ++r) {
                int q = r * 256 + tid;
                int row2 = q >> 4, ch2 = (q & 15) * 8;
                *(bfrag*)&Bs[row2 * 136 + ch2] = *(const bfrag*)&Lb[(n0 + row2) * NN + kc + ch2];
            }
        }
        __syncthreads();
#pragma unroll
        for (int ks = 0; ks < 4; ++ks) {
            bfrag a = *(const bfrag*)&As[lm * 136 + ks * 32 + lq * 8];
            bfrag bb = *(const bfrag*)&Bs[(wv * 16 + lm) * 136 + ks * 32 + lq * 8];
            acc = __builtin_amdgcn_mfma_f32_16x16x32_bf16(a, bb, acc, 0, 0, 0);
        }
    }
    // leapfrog epilogue: a_total = Tacc(A0) + acc(A1); zn = 2*Zc - Zo - H2*a_total
    const int n = n0 + wv * 16 + lm;
    float zn[4];
#pragma unroll
    for (int r = 0; r < 4; ++r) {
        int m = m0 + lq * 4 + r;
        float a = acc[r] + Tacc[(size_t)m * NN + n];
        float zc = Zc[(size_t)m * NN + n];
        float zo = Zo[(size_t)m * NN + n];
        zn[r] = 2.f * zc - zo - H2 * a;
        Zo[(size_t)m * NN + n] = zn[r];
    }
#pragma unroll
    for (int z = 0; z < 2; ++z)
#pragma unroll
        for (int r = 0; r < 4; ++r) {
            int ml = lq * 4 + r;
            float bz = BiasN[z * NOPEN + m0 + ml];
            Zt[z * 1024 + (wv * 16 + lm) * 16 + ml] = f2bf(zn[r] + bz);
        }
    __syncthreads();
    if (tid < 128) {
        int zz = tid >> 6, nl = tid & 63;
        bfrag v0 = *(const bfrag*)&Zt[zz * 1024 + nl * 16];
        bfrag v1 = *(const bfrag*)&Zt[zz * 1024 + nl * 16 + 8];
        ushort* dst = Zct + zz * (1032 * 128) + (size_t)(n0 + nl + 4) * 128 + m0;
        *(bfrag*)&dst[0] = v0;
        *(bfrag*)&dst[8] = v1;
    }
}

// ---------------- closing: out = concat(Kclose @ Zc, Kclose @ Zold) ----------------
__global__ void k_close(const float* __restrict__ Kclose, const float* __restrict__ Zc,
                        const float* __restrict__ Zold, float* __restrict__ out) {
    int n = blockIdx.x * 256 + threadIdx.x;
    int o = blockIdx.y;
    const float* Zb = blockIdx.z ? Zold : Zc;
    float a = 0.f;
#pragma unroll
    for (int c = 0; c < NOPEN; ++c) a = fmaf(Kclose[o * NOPEN + c], Zb[c * NN + n], a);
    out[blockIdx.z * (NCLOSE * NN) + o * NN + n] = a;
}

extern "C" void kernel_launch(void* const* d_in, const int* in_sizes, int n_in,
                              void* d_out, int out_size, void* d_ws, size_t ws_size,
                              hipStream_t stream) {
    const float* Z      = (const float*)d_in[0];
    const float* Kopen  = (const float*)d_in[1];
    const float* Kclose = (const float*)d_in[2];
    const float* W      = (const float*)d_in[3];
    const float* Bias   = (const float*)d_in[4];
    float* out = (float*)d_out;
    float* ws  = (float*)d_ws;

    // workspace layout (float units)
    float* Zb0   = ws + 0;         // 131072
    float* Zb1   = ws + 131072;    // 131072
    float* D2    = ws + 262144;    // 1048576
    float* C0    = ws + 1310720;   // 262144
    float* A1    = ws + 1572864;   // 262144
    float* Tacc  = ws + 1835008;   // 131072
    float* Stats = ws + 1966080;   // 1024 (sum0, sq0, sum1, sq1 x 256 ch)
    float* Dh    = ws + 5111808;   // 1024
    float* sig   = ws + 5112832;   // 1024
    ushort* Lb  = (ushort*)(ws + 5115904); // 1024*1024 us
    ushort* C1b = (ushort*)(ws + 5640192); // 256*1024 us
    ushort* T1b = (ushort*)(ws + 5771264); // 128*1024 us
    ushort* Zct = (ushort*)(ws + 5836800); // 2*1032*128 us
    ushort* Wf1 = (ushort*)(ws + 6233088); // 2*9*16*4*512 us (conv frags)
    ushort* Wf2 = (ushort*)(ws + 6528000); // 2*9*8*8*512 us  (convT frags)

    k_open<<<dim3(657), 256, 0, stream>>>(Kopen, Z, Zb0, Zb1, Bias, Zct,
                                          W, Wf1, Wf2, sig, Stats);

    float* Zc = Zb0;
    float* Zold = Zb1;
    for (int i = 0; i < NLAYERS; ++i) {
        if (i % 10 == 0) {
            k_d2<<<dim3(16, 32), 256, 0, stream>>>(Zc, D2, sig);
            k_deg<<<dim3(NN), 256, 0, stream>>>(D2, sig, Dh);
            k_L<<<dim3(NN), 256, 0, stream>>>(D2, sig, Dh, Lb);
        }
        k_conv<<<dim3(16, 8, 2), 256, 0, stream>>>(Zct, Wf1, C0, C1b, Stats);
        k_xl1<<<dim3(8, 8), 256, 0, stream>>>(C1b, Lb, A1, Stats);
        k_nct<<<dim3(16, 2, 2), 256, 0, stream>>>(C0, A1, Stats, Wf2, Tacc, T1b);
        int lnext = (i + 1 < NLAYERS) ? i + 1 : NLAYERS - 1;
        k_xl2leap<<<dim3(273), 256, 0, stream>>>(T1b, Lb, Tacc, Zc, Zold,
                                                 Bias + (size_t)lnext * 2 * NOPEN, Zct,
                                                 W, Wf1, Wf2, Stats, sig, lnext,
                                                 (i + 1 < NLAYERS) ? 1 : 0);
        float* tmp = Zc; Zc = Zold; Zold = tmp;
    }

    k_close<<<dim3(4, NCLOSE, 2), 256, 0, stream>>>(Kclose, Zc, Zold, out);
}

// Round 4
// 2249.390 us; speedup vs baseline: 1.4752x; 1.4752x over previous
//
#include <hip/hip_runtime.h>

#define NN 1024
#define NOPEN 128
#define NHID 256
#define NSTART 40
#define NCLOSE 3
#define NLAYERS 40
#define KSZ 9

static constexpr float H2 = 0.01f;     // h*h, h = 0.1
static constexpr float IN_EPS = 1e-5f; // instance norm eps

using floatx4 = __attribute__((ext_vector_type(4))) float;
using bfrag = __attribute__((ext_vector_type(8))) short; // 8 bf16 = 4 VGPRs

__device__ __forceinline__ ushort f2bf(float f) {
    union { float f; unsigned u; } v; v.f = f;
    unsigned r = v.u + 0x7fffu + ((v.u >> 16) & 1u); // RNE
    return (ushort)(r >> 16);
}

// weight prep in MFMA-fragment-major order:
// Wf1: conv A-frags:  frag index ((z*9+t)*16 + g)*4 + kc   (g = co-tile of 16, kc = k-quad of 32)
// Wf2: convT A-frags: frag index ((z*9+t)*8 + g)*8 + j     (g = ci-tile of 16, j = k-oct of 32)
// each frag = 512 ushorts = 1KB (64 lanes x 16B), one coalesced dwordx4 per wave.
__device__ __forceinline__ void prepw_piece(const float* __restrict__ W, ushort* __restrict__ Wf1,
                                            ushort* __restrict__ Wf2, int lb, int lsrc, int tid) {
    if (lb < 72) {
        int z = lb / 36, rem = lb % 36;
        int t = rem >> 2, q = rem & 3;
        const float* Wz = W + (size_t)(lsrc * 2 + z) * (NHID * NOPEN * KSZ);
        ushort* dst = Wf1 + (((size_t)(z * 9 + t) * 64 + q * 16) << 9);
#pragma unroll
        for (int r = 0; r < 32; ++r) {
            int ei = r * 256 + tid;
            int g = q * 4 + (ei >> 11);
            int kc = (ei >> 9) & 3;
            int lm = (ei >> 3) & 15, lq = (ei >> 7) & 3;
            int e = ei & 7;
            int co = g * 16 + lm, ci = kc * 32 + lq * 8 + e;
            dst[ei] = f2bf(Wz[co * (NOPEN * KSZ) + ci * KSZ + t]);
        }
    } else {
        int p2 = lb - 72;
        int z = p2 / 36, rem = p2 % 36;
        int t = rem >> 2, q = rem & 3;
        const float* Wz = W + (size_t)(lsrc * 2 + z) * (NHID * NOPEN * KSZ);
        ushort* dst = Wf2 + (((size_t)(z * 9 + t) * 64 + q * 16) << 9);
#pragma unroll
        for (int r = 0; r < 32; ++r) {
            int ei = r * 256 + tid;
            int fb = q * 16 + (ei >> 9);
            int g = fb >> 3, j = fb & 7;
            int lm = (ei >> 3) & 15, lq = (ei >> 7) & 3;
            int e = ei & 7;
            int ci = g * 16 + lm, co = j * 32 + lq * 8 + e;
            dst[ei] = f2bf(Wz[co * (NOPEN * KSZ) + ci * KSZ + t]);
        }
    }
}

// ---------------- opening: Zc/Zold/Zct(layer0) + weight prep(layer0) + pads + sig/Stats=0 + A1=0 ----------------
__global__ __launch_bounds__(256) void k_open(const float* __restrict__ Kopen, const float* __restrict__ Z,
                       float* __restrict__ Zc, float* __restrict__ Zold,
                       const float* __restrict__ Bias0, ushort* __restrict__ Zct,
                       ushort* __restrict__ At0, ushort* __restrict__ At1,
                       const float* __restrict__ W, ushort* __restrict__ Wf1,
                       ushort* __restrict__ Wf2, float* __restrict__ sig,
                       float* __restrict__ A1, float* __restrict__ Stats) {
    const int v = blockIdx.x, tid = threadIdx.x;
    if (v < 512) {
        int o = v >> 2, n = (v & 3) * 256 + tid;
        float acc = 0.f;
#pragma unroll
        for (int s = 0; s < NSTART; ++s)
            acc = fmaf(Kopen[o * NSTART + s], Z[s * NN + n], acc);
        Zc[o * NN + n] = acc;
        Zold[o * NN + n] = acc;
#pragma unroll
        for (int z = 0; z < 2; ++z)
            Zct[z * (1032 * 128) + (n + 4) * 128 + o] = f2bf(acc + Bias0[z * NOPEN + o]);
    } else if (v < 656) {
        prepw_piece(W, Wf1, Wf2, v - 512, 0, tid);
    } else if (v == 656) {
        if (tid == 0) sig[0] = 0.f;
        for (int idx = tid; idx < 512; idx += 256) Stats[idx] = 0.f;
        for (int idx = tid; idx < 1024; idx += 256) {
            int z = idx >> 9, rr = idx & 511;
            ushort* Zz = Zct + z * (1032 * 128);
            Zz[rr] = 0; Zz[1028 * 128 + rr] = 0;
        }
        for (int idx = tid; idx < 2048; idx += 256) {
            int a = idx >> 10, rr = idx & 1023;
            ushort* A = a ? At1 : At0;
            A[rr] = 0; A[1028 * 256 + rr] = 0;
        }
    } else {
        // v in [657, 721): zero A1 for layer 0's atomic accumulation
        int b = v - 657;
        size_t base = (size_t)b * 4096 + tid * 4;
        float4 z4 = {0.f, 0.f, 0.f, 0.f};
#pragma unroll
        for (int r = 0; r < 4; ++r) *(float4*)&A1[base + r * 1024] = z4;
    }
}

// ---------------- D2 = max(sq_i + sq_j - 2 Z^T Z, 0); sum(D2) -> sig ----------------
__global__ __launch_bounds__(256) void k_d2(const float* __restrict__ Zc,
                                            float* __restrict__ D2, float* __restrict__ sig) {
    __shared__ __align__(16) float Zi[32 * 36];
    __shared__ __align__(16) float Zj[32 * 68];
    __shared__ float sqi[32], sqj[64];
    __shared__ float red[4];
    const int tid = threadIdx.x;
    const int tx = tid & 15, ty = tid >> 4;
    const int j0 = blockIdx.x * 64, i0 = blockIdx.y * 32;
    if (tid < 32) sqi[tid] = 0.f;
    else if (tid < 96) sqj[tid - 32] = 0.f;
    float acc[2][4] = {};
    for (int c0 = 0; c0 < NOPEN; c0 += 32) {
        for (int idx = tid; idx < 32 * 32; idx += 256) {
            int c = idx >> 5, ii = idx & 31;
            Zi[c * 36 + ii] = Zc[(c0 + c) * NN + i0 + ii];
        }
        for (int idx = tid; idx < 32 * 64; idx += 256) {
            int c = idx >> 6, jj = idx & 63;
            Zj[c * 68 + jj] = Zc[(c0 + c) * NN + j0 + jj];
        }
        __syncthreads();
        if (tid < 32) {
            float s = 0.f;
            for (int c = 0; c < 32; ++c) { float x = Zi[c * 36 + tid]; s = fmaf(x, x, s); }
            sqi[tid] += s;
        } else if (tid < 96) {
            int jj = tid - 32;
            float s = 0.f;
            for (int c = 0; c < 32; ++c) { float x = Zj[c * 68 + jj]; s = fmaf(x, x, s); }
            sqj[jj] += s;
        }
#pragma unroll 8
        for (int c = 0; c < 32; ++c) {
            float2 zi = *(const float2*)&Zi[c * 36 + ty * 2];
            float4 zj = *(const float4*)&Zj[c * 68 + tx * 4];
            acc[0][0] = fmaf(zi.x, zj.x, acc[0][0]);
            acc[0][1] = fmaf(zi.x, zj.y, acc[0][1]);
            acc[0][2] = fmaf(zi.x, zj.z, acc[0][2]);
            acc[0][3] = fmaf(zi.x, zj.w, acc[0][3]);
            acc[1][0] = fmaf(zi.y, zj.x, acc[1][0]);
            acc[1][1] = fmaf(zi.y, zj.y, acc[1][1]);
            acc[1][2] = fmaf(zi.y, zj.z, acc[1][2]);
            acc[1][3] = fmaf(zi.y, zj.w, acc[1][3]);
        }
        __syncthreads();
    }
    float part = 0.f;
#pragma unroll
    for (int m = 0; m < 2; ++m) {
        int i = i0 + ty * 2 + m;
        float sqi_v = sqi[ty * 2 + m];
        float4 d;
        d.x = fmaxf(sqi_v + sqj[tx * 4 + 0] - 2.f * acc[m][0], 0.f);
        d.y = fmaxf(sqi_v + sqj[tx * 4 + 1] - 2.f * acc[m][1], 0.f);
        d.z = fmaxf(sqi_v + sqj[tx * 4 + 2] - 2.f * acc[m][2], 0.f);
        d.w = fmaxf(sqi_v + sqj[tx * 4 + 3] - 2.f * acc[m][3], 0.f);
        *(float4*)&D2[(size_t)i * NN + j0 + tx * 4] = d;
        part += (d.x + d.y) + (d.z + d.w);
    }
#pragma unroll
    for (int off = 32; off > 0; off >>= 1) part += __shfl_down(part, off);
    if ((tid & 63) == 0) red[tid >> 6] = part;
    __syncthreads();
    if (tid == 0) atomicAdd(sig, red[0] + red[1] + red[2] + red[3]);
}

// ---------------- deg_i = sum_j exp(-D2_ij/sigma); Dh_i = rsqrt(deg_i) ----------------
__global__ void k_deg(const float* __restrict__ D2, const float* __restrict__ sig,
                      float* __restrict__ Dh) {
    __shared__ float red[4];
    int i = blockIdx.x, tid = threadIdx.x;
    float inv = 1.f / (sig[0] * (1.f / 1048576.f) + 1e-12f);
    float4 v = *(const float4*)&D2[(size_t)i * NN + tid * 4];
    float s = __expf(-v.x * inv) + __expf(-v.y * inv) + __expf(-v.z * inv) + __expf(-v.w * inv);
#pragma unroll
    for (int off = 32; off > 0; off >>= 1) s += __shfl_down(s, off);
    if ((tid & 63) == 0) red[tid >> 6] = s;
    __syncthreads();
    if (tid == 0) Dh[i] = rsqrtf(red[0] + red[1] + red[2] + red[3]);
}

// ---------------- Lb_ij = bf16( delta_ij - Dh_i Dh_j exp(-D2_ij/sigma) ) ----------------
__global__ void k_L(const float* __restrict__ D2, const float* __restrict__ sig,
                    const float* __restrict__ Dh, ushort* __restrict__ Lb) {
    int i = blockIdx.x, tid = threadIdx.x;
    int j = tid * 4;
    float inv = 1.f / (sig[0] * (1.f / 1048576.f) + 1e-12f);
    float dhi = Dh[i];
    float4 v = *(const float4*)&D2[(size_t)i * NN + j];
    float4 dj = *(const float4*)&Dh[j];
    float4 o;
    o.x = -dhi * dj.x * __expf(-v.x * inv);
    o.y = -dhi * dj.y * __expf(-v.y * inv);
    o.z = -dhi * dj.z * __expf(-v.z * inv);
    o.w = -dhi * dj.w * __expf(-v.w * inv);
    if (i == j + 0) o.x += 1.f;
    if (i == j + 1) o.y += 1.f;
    if (i == j + 2) o.z += 1.f;
    if (i == j + 3) o.w += 1.f;
    ushort4 ob; ob.x = f2bf(o.x); ob.y = f2bf(o.y); ob.z = f2bf(o.z); ob.w = f2bf(o.w);
    *(ushort4*)&Lb[(size_t)i * NN + j] = ob;
}

// ---------------- MFMA conv1d + fused C0 stats: C[co,p] = sum_{t,ci} W[t][co][ci]*Zct[p+t][ci] ----------------
// grid (16 p, 8 co, 2 z); z=0 blocks atomically accumulate per-channel sum/sumsq into Stats[0/256]
__global__ __launch_bounds__(256) void k_conv(const ushort* __restrict__ Zct,
        const ushort* __restrict__ Wf1, float* __restrict__ C0, ushort* __restrict__ C1b,
        float* __restrict__ Stats) {
    const int z = blockIdx.z;
    const int p0 = blockIdx.x * 64, co0 = blockIdx.y * 32;
    __shared__ ushort Xs[72 * 136];
    const int tid = threadIdx.x;
    const ushort* Zz = Zct + z * (1032 * 128);
    for (int idx = tid; idx < 1152; idx += 256) {
        int row = idx >> 4, ch = (idx & 15) * 8;
        *(bfrag*)&Xs[row * 136 + ch] = *(const bfrag*)&Zz[(p0 + row) * 128 + ch];
    }
    __syncthreads();
    const int l = tid & 63, wv = tid >> 6;
    const int wm = wv >> 1, wn = wv & 1;
    const int lm = l & 15, lq = l >> 4;
    const ushort* wf = Wf1 + (((size_t)z * 144 + (blockIdx.y * 2 + wm)) << 11) + l * 8;
    floatx4 acc[2] = {};
    bfrag a_cur[4];
#pragma unroll
    for (int kc = 0; kc < 4; ++kc) a_cur[kc] = *(const bfrag*)(wf + (kc << 9));
    for (int t = 0; t < 9; ++t) {
        bfrag a_nxt[4];
        if (t < 8) {
            const ushort* wptr = wf + (size_t)(t + 1) * (16 << 11);
#pragma unroll
            for (int kc = 0; kc < 4; ++kc) a_nxt[kc] = *(const bfrag*)(wptr + (kc << 9));
        }
        const int xbase = (wn * 32 + lm + t) * 136 + lq * 8;
#pragma unroll
        for (int kc = 0; kc < 4; ++kc) {
            bfrag b0 = *(const bfrag*)&Xs[xbase + kc * 32];
            acc[0] = __builtin_amdgcn_mfma_f32_16x16x32_bf16(a_cur[kc], b0, acc[0], 0, 0, 0);
            bfrag b1 = *(const bfrag*)&Xs[xbase + 16 * 136 + kc * 32];
            acc[1] = __builtin_amdgcn_mfma_f32_16x16x32_bf16(a_cur[kc], b1, acc[1], 0, 0, 0);
        }
#pragma unroll
        for (int kc = 0; kc < 4; ++kc) a_cur[kc] = a_nxt[kc];
    }
    const int cog = co0 + wm * 16 + lq * 4;
    const int pg = p0 + wn * 32 + lm;
#pragma unroll
    for (int j = 0; j < 2; ++j)
#pragma unroll
        for (int r = 0; r < 4; ++r) {
            if (z == 0) C0[(cog + r) * NN + pg + j * 16] = acc[j][r];
            else        C1b[(cog + r) * NN + pg + j * 16] = f2bf(acc[j][r]);
        }
    if (z == 0) {
        float s[4], q2[4];
#pragma unroll
        for (int r = 0; r < 4; ++r) {
            s[r] = acc[0][r] + acc[1][r];
            q2[r] = acc[0][r] * acc[0][r] + acc[1][r] * acc[1][r];
        }
#pragma unroll
        for (int off = 1; off < 16; off <<= 1)
#pragma unroll
            for (int r = 0; r < 4; ++r) {
                s[r] += __shfl_xor(s[r], off);
                q2[r] += __shfl_xor(q2[r], off);
            }
        if (lm == 0)
#pragma unroll
            for (int r = 0; r < 4; ++r) {
                atomicAdd(&Stats[cog + r], s[r]);
                atomicAdd(&Stats[256 + cog + r], q2[r]);
            }
    }
}

// ---------------- MFMA split-K GEMM with atomic accumulate: Out += X[:, kc:kc+128] @ L[kc:kc+128, :] ----------------
// grid (8 nt, M/64 mt, 8 ksp); Out must be zeroed (A1) or pre-seeded (Tacc = convT z0 output) beforehand
__global__ __launch_bounds__(256) void k_xl_mfma(const ushort* __restrict__ X,
                                                 const ushort* __restrict__ Lb,
                                                 float* __restrict__ Out) {
    __shared__ __align__(16) ushort As[64 * 136];
    __shared__ __align__(16) ushort Bs[128 * 136];
    const int tid = threadIdx.x;
    const int lane = tid & 63, wave = tid >> 6;
    const int wm = wave >> 1, wn = wave & 1;
    const int n0 = blockIdx.x * 128, m0 = blockIdx.y * 64, kc = blockIdx.z * 128;
    {
        int q = tid;
#pragma unroll
        for (int r = 0; r < 4; ++r, q += 256) {
            int row = q >> 4, ch = (q & 15) * 8;
            *(bfrag*)&As[row * 136 + ch] = *(const bfrag*)&X[(m0 + row) * NN + kc + ch];
        }
        q = tid;
#pragma unroll
        for (int r = 0; r < 8; ++r, q += 256) {
            int row = q >> 4, ch = (q & 15) * 8;
            *(bfrag*)&Bs[row * 136 + ch] = *(const bfrag*)&Lb[(n0 + row) * NN + kc + ch];
        }
    }
    __syncthreads();
    floatx4 acc[2][4] = {};
    const int lrow = (lane & 15) * 136;
    const int koff = (lane >> 4) * 8;
#pragma unroll
    for (int ks = 0; ks < 4; ++ks) {
        bfrag a[2], b[4];
#pragma unroll
        for (int i = 0; i < 2; ++i)
            a[i] = *(const bfrag*)&As[(wm * 32 + i * 16) * 136 + lrow + ks * 32 + koff];
#pragma unroll
        for (int j = 0; j < 4; ++j)
            b[j] = *(const bfrag*)&Bs[(wn * 64 + j * 16) * 136 + lrow + ks * 32 + koff];
#pragma unroll
        for (int i = 0; i < 2; ++i)
#pragma unroll
            for (int j = 0; j < 4; ++j)
                acc[i][j] = __builtin_amdgcn_mfma_f32_16x16x32_bf16(a[i], b[j], acc[i][j], 0, 0, 0);
    }
    const int mg0 = m0 + wm * 32 + (lane >> 4) * 4;
    const int ng0 = n0 + wn * 64 + (lane & 15);
#pragma unroll
    for (int i = 0; i < 2; ++i)
#pragma unroll
        for (int j = 0; j < 4; ++j)
#pragma unroll
            for (int r = 0; r < 4; ++r)
                atomicAdd(&Out[(size_t)(mg0 + i * 16 + r) * NN + ng0 + j * 16], acc[i][j][r]);
}

// ---------------- fused instance-norm stats + normalize + relu + bf16 + transpose -> At[pos+4][co] ----------------
// grid (16 p, 4 co64, 2 arr). arr=0 stats from Stats (exact, conv epilogue); arr=1 recomputed in-block from A1.
__global__ __launch_bounds__(256) void k_normT(const float* __restrict__ C0,
        const float* __restrict__ A1, const float* __restrict__ Stats,
        ushort* __restrict__ At0, ushort* __restrict__ At1) {
    const int arr = blockIdx.z;
    const int p0 = blockIdx.x * 64, co0 = blockIdx.y * 64;
    const float* in = arr ? A1 : C0;
    ushort* out = arr ? At1 : At0;
    __shared__ ushort Ls[64 * 72];
    __shared__ float mu[64], rs[64];
    __shared__ float pS[256], pQ[256];
    const int tid = threadIdx.x;
    if (arr == 0) {
        if (tid < 64) {
            int co = co0 + tid;
            float S = Stats[co], Q = Stats[256 + co];
            float mean = S * (1.f / NN);
            float var = Q * (1.f / NN) - mean * mean;
            mu[tid] = mean;
            rs[tid] = rsqrtf(var + IN_EPS);
        }
    } else {
        int ch = tid >> 2, sub = tid & 3;
        const float* row = in + (size_t)(co0 + ch) * NN;
        float s = 0.f, qq = 0.f;
        for (int k = 0; k < 64; ++k) {
            float4 v = *(const float4*)&row[k * 16 + sub * 4];
            s += (v.x + v.y) + (v.z + v.w);
            qq += (v.x * v.x + v.y * v.y) + (v.z * v.z + v.w * v.w);
        }
        pS[tid] = s; pQ[tid] = qq;
        __syncthreads();
        if (tid < 64) {
            int base = tid * 4;
            float S = (pS[base] + pS[base + 1]) + (pS[base + 2] + pS[base + 3]);
            float Q = (pQ[base] + pQ[base + 1]) + (pQ[base + 2] + pQ[base + 3]);
            float mean = S * (1.f / NN);
            float var = Q * (1.f / NN) - mean * mean;
            mu[tid] = mean;
            rs[tid] = rsqrtf(var + IN_EPS);
        }
    }
    __syncthreads();
#pragma unroll
    for (int r = 0; r < 4; ++r) {
        int idx = r * 256 + tid;      // 64 co x 16 p-chunks(4)
        int col = idx >> 4, pq = idx & 15;
        float4 v = *(const float4*)&in[(size_t)(co0 + col) * NN + p0 + pq * 4];
        float m = mu[col], sc = rs[col];
        Ls[(pq * 4 + 0) * 72 + col] = f2bf(fmaxf((v.x - m) * sc, 0.f));
        Ls[(pq * 4 + 1) * 72 + col] = f2bf(fmaxf((v.y - m) * sc, 0.f));
        Ls[(pq * 4 + 2) * 72 + col] = f2bf(fmaxf((v.z - m) * sc, 0.f));
        Ls[(pq * 4 + 3) * 72 + col] = f2bf(fmaxf((v.w - m) * sc, 0.f));
    }
    __syncthreads();
#pragma unroll
    for (int r = 0; r < 2; ++r) {
        int idx = r * 256 + tid;      // 64 rows x 8 chunks(8)
        int row = idx >> 3, ch = (idx & 7) * 8;
        *(bfrag*)&out[(size_t)(p0 + row + 4) * 256 + co0 + ch] = *(const bfrag*)&Ls[row * 72 + ch];
    }
}

// ---------------- MFMA convT: T[ci,p] = sum_{t,co} W[t][ci][co] * At[p+8-t][co] ----------------
// W read directly from global fragment-major (no W LDS); LDS = Al only (38 KB)
// grid (16 p, 8 ci16, 2 z); block tile 16ci x 64p; single barrier
__global__ __launch_bounds__(256) void k_convT(const ushort* __restrict__ At0,
        const ushort* __restrict__ At1, const ushort* __restrict__ Wf2,
        float* __restrict__ Tacc, ushort* __restrict__ T1b) {
    const int z = blockIdx.z;
    const int p0 = blockIdx.x * 64, ci0 = blockIdx.y * 16;
    __shared__ ushort Al[72 * 264];
    const ushort* A = z ? At1 : At0;
    const int tid = threadIdx.x;
    for (int idx = tid; idx < 2304; idx += 256) {
        int row = idx >> 5, ch = (idx & 31) * 8;
        *(bfrag*)&Al[row * 264 + ch] = *(const bfrag*)&A[(p0 + row) * 256 + ch];
    }
    __syncthreads();
    const int l = tid & 63, wv = tid >> 6;
    const int lm = l & 15, lq = l >> 4;
    const ushort* wf = Wf2 + (((size_t)z * 72 + blockIdx.y) << 12) + l * 8;
    floatx4 acc0 = {}, acc1 = {};
    bfrag a_cur[8];
#pragma unroll
    for (int j = 0; j < 8; ++j) a_cur[j] = *(const bfrag*)(wf + (j << 9));
    for (int t = 0; t < 9; ++t) {
        bfrag a_nxt[8];
        if (t < 8) {
            const ushort* wptr = wf + (size_t)(t + 1) * (8 << 12);
#pragma unroll
            for (int j = 0; j < 8; ++j) a_nxt[j] = *(const bfrag*)(wptr + (j << 9));
        }
        const int abase = (wv * 16 + lm + 8 - t) * 264 + lq * 8;
#pragma unroll
        for (int j = 0; j < 8; j += 2) {
            bfrag b0 = *(const bfrag*)&Al[abase + j * 32];
            acc0 = __builtin_amdgcn_mfma_f32_16x16x32_bf16(a_cur[j], b0, acc0, 0, 0, 0);
            bfrag b1 = *(const bfrag*)&Al[abase + j * 32 + 32];
            acc1 = __builtin_amdgcn_mfma_f32_16x16x32_bf16(a_cur[j + 1], b1, acc1, 0, 0, 0);
        }
#pragma unroll
        for (int j = 0; j < 8; ++j) a_cur[j] = a_nxt[j];
    }
    floatx4 acc = acc0 + acc1;
    const int cig = ci0 + lq * 4;
    const int pg = p0 + wv * 16 + lm;
#pragma unroll
    for (int r = 0; r < 4; ++r) {
        if (z == 0) Tacc[(cig + r) * NN + pg] = acc[r];
        else        T1b[(cig + r) * NN + pg] = f2bf(acc[r]);
    }
}

// ---------------- leapfrog (Tacc already = convT + XL2 via atomics) + next Zct + prepw + sig/Stats=0 + A1=0 ----------------
// grid 337: v<128 leap; 128..271 prepw(lnext) if doprep; v=272 zero sig+Stats; 273..336 zero A1
__global__ __launch_bounds__(256) void k_leap(const float* __restrict__ Tacc,
        const float* __restrict__ Zc, float* __restrict__ Zo,
        const float* __restrict__ BiasN, ushort* __restrict__ Zct,
        const float* __restrict__ W, ushort* __restrict__ Wf1, ushort* __restrict__ Wf2,
        float* __restrict__ A1, float* __restrict__ Stats, float* __restrict__ sig,
        int lnext, int doprep) {
    const int v = blockIdx.x, tid = threadIdx.x;
    if (v < 128) {
        int off = (v * 256 + tid) * 4;
        float4 a = *(const float4*)&Tacc[off];
        float4 zc = *(const float4*)&Zc[off];
        float4 zo = *(const float4*)&Zo[off];
        float4 zn;
        zn.x = 2.f * zc.x - zo.x - H2 * a.x;
        zn.y = 2.f * zc.y - zo.y - H2 * a.y;
        zn.z = 2.f * zc.z - zo.z - H2 * a.z;
        zn.w = 2.f * zc.w - zo.w - H2 * a.w;
        *(float4*)&Zo[off] = zn;
        int ci = off >> 10, n = off & 1023;
#pragma unroll
        for (int z = 0; z < 2; ++z) {
            float bz = BiasN[z * NOPEN + ci];
            ushort* Zz = Zct + z * (1032 * 128);
            Zz[(n + 4) * 128 + ci] = f2bf(zn.x + bz);
            Zz[(n + 5) * 128 + ci] = f2bf(zn.y + bz);
            Zz[(n + 6) * 128 + ci] = f2bf(zn.z + bz);
            Zz[(n + 7) * 128 + ci] = f2bf(zn.w + bz);
        }
    } else if (v < 272) {
        if (doprep) prepw_piece(W, Wf1, Wf2, v - 128, lnext, tid);
    } else if (v == 272) {
        if (tid == 0) sig[0] = 0.f;
        if (tid < 128) {
            float4 z4 = {0.f, 0.f, 0.f, 0.f};
            *(float4*)&Stats[tid * 4] = z4;
        }
    } else {
        // v in [273, 337): zero A1 for next layer's atomic accumulation
        int b = v - 273;
        size_t base = (size_t)b * 4096 + tid * 4;
        float4 z4 = {0.f, 0.f, 0.f, 0.f};
#pragma unroll
        for (int r = 0; r < 4; ++r) *(float4*)&A1[base + r * 1024] = z4;
    }
}

// ---------------- closing: out = concat(Kclose @ Zc, Kclose @ Zold) ----------------
__global__ void k_close(const float* __restrict__ Kclose, const float* __restrict__ Zc,
                        const float* __restrict__ Zold, float* __restrict__ out) {
    int n = blockIdx.x * 256 + threadIdx.x;
    int o = blockIdx.y;
    const float* Zb = blockIdx.z ? Zold : Zc;
    float a = 0.f;
#pragma unroll
    for (int c = 0; c < NOPEN; ++c) a = fmaf(Kclose[o * NOPEN + c], Zb[c * NN + n], a);
    out[blockIdx.z * (NCLOSE * NN) + o * NN + n] = a;
}

extern "C" void kernel_launch(void* const* d_in, const int* in_sizes, int n_in,
                              void* d_out, int out_size, void* d_ws, size_t ws_size,
                              hipStream_t stream) {
    const float* Z      = (const float*)d_in[0];
    const float* Kopen  = (const float*)d_in[1];
    const float* Kclose = (const float*)d_in[2];
    const float* W      = (const float*)d_in[3];
    const float* Bias   = (const float*)d_in[4];
    float* out = (float*)d_out;
    float* ws  = (float*)d_ws;

    // workspace layout (float units)
    float* Zb0   = ws + 0;         // 131072
    float* Zb1   = ws + 131072;    // 131072
    float* D2    = ws + 262144;    // 1048576
    float* C0    = ws + 1310720;   // 262144
    float* A1    = ws + 1572864;   // 262144
    float* Tacc  = ws + 1835008;   // 131072
    float* Dh    = ws + 5111808;   // 1024
    float* sig   = ws + 5112832;   // 1024
    float* Stats = ws + 5113856;   // 1024 (512 used: sum0, sq0)
    ushort* Lb  = (ushort*)(ws + 5115904); // 1024*1024 us
    ushort* C1b = (ushort*)(ws + 5640192); // 256*1024 us
    ushort* T1b = (ushort*)(ws + 5771264); // 128*1024 us
    ushort* Zct = (ushort*)(ws + 5836800); // 2*1032*128 us
    ushort* At0 = (ushort*)(ws + 5968896); // 1032*256 us
    ushort* At1 = (ushort*)(ws + 6100992); // 1032*256 us
    ushort* Wf1 = (ushort*)(ws + 6233088); // 2*9*16*4*512 us (conv frags)
    ushort* Wf2 = (ushort*)(ws + 6528000); // 2*9*8*8*512 us  (convT frags)

    k_open<<<dim3(721), 256, 0, stream>>>(Kopen, Z, Zb0, Zb1, Bias, Zct, At0, At1,
                                          W, Wf1, Wf2, sig, A1, Stats);

    float* Zc = Zb0;
    float* Zold = Zb1;
    for (int i = 0; i < NLAYERS; ++i) {
        if (i % 10 == 0) {
            k_d2<<<dim3(16, 32), 256, 0, stream>>>(Zc, D2, sig);
            k_deg<<<dim3(NN), 256, 0, stream>>>(D2, sig, Dh);
            k_L<<<dim3(NN), 256, 0, stream>>>(D2, sig, Dh, Lb);
        }
        k_conv<<<dim3(16, 8, 2), 256, 0, stream>>>(Zct, Wf1, C0, C1b, Stats);
        k_xl_mfma<<<dim3(8, 4, 8), 256, 0, stream>>>(C1b, Lb, A1);    // XL1 -> A1 (zeroed)
        k_normT<<<dim3(16, 4, 2), 256, 0, stream>>>(C0, A1, Stats, At0, At1);
        k_convT<<<dim3(16, 8, 2), 256, 0, stream>>>(At0, At1, Wf2, Tacc, T1b);
        k_xl_mfma<<<dim3(8, 2, 8), 256, 0, stream>>>(T1b, Lb, Tacc);  // XL2 += into Tacc
        int lnext = (i + 1 < NLAYERS) ? i + 1 : NLAYERS - 1;
        k_leap<<<dim3(337), 256, 0, stream>>>(Tacc, Zc, Zold,
                                              Bias + (size_t)lnext * 2 * NOPEN, Zct,
                                              W, Wf1, Wf2, A1, Stats, sig, lnext,
                                              (i + 1 < NLAYERS) ? 1 : 0);
        float* tmp = Zc; Zc = Zold; Zold = tmp;
    }

    k_close<<<dim3(4, NCLOSE, 2), 256, 0, stream>>>(Kclose, Zc, Zold, out);
}

// Round 5
// 1873.719 us; speedup vs baseline: 1.7710x; 1.2005x over previous
//
#include <hip/hip_runtime.h>

#define NN 1024
#define NOPEN 128
#define NHID 256
#define NSTART 40
#define NCLOSE 3
#define NLAYERS 40
#define KSZ 9

static constexpr float H2 = 0.01f;     // h*h, h = 0.1
static constexpr float IN_EPS = 1e-5f; // instance norm eps

using floatx4 = __attribute__((ext_vector_type(4))) float;
using bfrag = __attribute__((ext_vector_type(8))) short; // 8 bf16 = 4 VGPRs

__device__ __forceinline__ ushort f2bf(float f) {
    union { float f; unsigned u; } v; v.f = f;
    unsigned r = v.u + 0x7fffu + ((v.u >> 16) & 1u); // RNE
    return (ushort)(r >> 16);
}

// weight prep in MFMA-fragment-major order:
// Wf1: conv A-frags:  frag index ((z*9+t)*16 + g)*4 + kc   (g = co-tile of 16, kc = k-quad of 32)
// Wf2: convT A-frags: frag index ((z*9+t)*8 + g)*8 + j     (g = ci-tile of 16, j = k-oct of 32)
// each frag = 512 ushorts = 1KB (64 lanes x 16B), one coalesced dwordx4 per wave.
__device__ __forceinline__ void prepw_piece(const float* __restrict__ W, ushort* __restrict__ Wf1,
                                            ushort* __restrict__ Wf2, int lb, int lsrc, int tid) {
    if (lb < 72) {
        int z = lb / 36, rem = lb % 36;
        int t = rem >> 2, q = rem & 3;
        const float* Wz = W + (size_t)(lsrc * 2 + z) * (NHID * NOPEN * KSZ);
        ushort* dst = Wf1 + (((size_t)(z * 9 + t) * 64 + q * 16) << 9);
#pragma unroll
        for (int r = 0; r < 32; ++r) {
            int ei = r * 256 + tid;
            int g = q * 4 + (ei >> 11);
            int kc = (ei >> 9) & 3;
            int lm = (ei >> 3) & 15, lq = (ei >> 7) & 3;
            int e = ei & 7;
            int co = g * 16 + lm, ci = kc * 32 + lq * 8 + e;
            dst[ei] = f2bf(Wz[co * (NOPEN * KSZ) + ci * KSZ + t]);
        }
    } else {
        int p2 = lb - 72;
        int z = p2 / 36, rem = p2 % 36;
        int t = rem >> 2, q = rem & 3;
        const float* Wz = W + (size_t)(lsrc * 2 + z) * (NHID * NOPEN * KSZ);
        ushort* dst = Wf2 + (((size_t)(z * 9 + t) * 64 + q * 16) << 9);
#pragma unroll
        for (int r = 0; r < 32; ++r) {
            int ei = r * 256 + tid;
            int fb = q * 16 + (ei >> 9);
            int g = fb >> 3, j = fb & 7;
            int lm = (ei >> 3) & 15, lq = (ei >> 7) & 3;
            int e = ei & 7;
            int ci = g * 16 + lm, co = j * 32 + lq * 8 + e;
            dst[ei] = f2bf(Wz[co * (NOPEN * KSZ) + ci * KSZ + t]);
        }
    }
}

// ---------------- opening: Zc/Zold/Zct(layer0) + weight prep(layer0) + pads + sig=0 + A1=0 ----------------
__global__ __launch_bounds__(256) void k_open(const float* __restrict__ Kopen, const float* __restrict__ Z,
                       float* __restrict__ Zc, float* __restrict__ Zold,
                       const float* __restrict__ Bias0, ushort* __restrict__ Zct,
                       ushort* __restrict__ At0, ushort* __restrict__ At1,
                       const float* __restrict__ W, ushort* __restrict__ Wf1,
                       ushort* __restrict__ Wf2, float* __restrict__ sig, float* __restrict__ A1) {
    const int v = blockIdx.x, tid = threadIdx.x;
    if (v < 512) {
        int o = v >> 2, n = (v & 3) * 256 + tid;
        float acc = 0.f;
#pragma unroll
        for (int s = 0; s < NSTART; ++s)
            acc = fmaf(Kopen[o * NSTART + s], Z[s * NN + n], acc);
        Zc[o * NN + n] = acc;
        Zold[o * NN + n] = acc;
#pragma unroll
        for (int z = 0; z < 2; ++z)
            Zct[z * (1032 * 128) + (n + 4) * 128 + o] = f2bf(acc + Bias0[z * NOPEN + o]);
    } else if (v < 656) {
        prepw_piece(W, Wf1, Wf2, v - 512, 0, tid);
    } else if (v == 656) {
        if (tid == 0) sig[0] = 0.f;
        for (int idx = tid; idx < 1024; idx += 256) {
            int z = idx >> 9, rr = idx & 511;
            ushort* Zz = Zct + z * (1032 * 128);
            Zz[rr] = 0; Zz[1028 * 128 + rr] = 0;
        }
        for (int idx = tid; idx < 2048; idx += 256) {
            int a = idx >> 10, rr = idx & 1023;
            ushort* A = a ? At1 : At0;
            A[rr] = 0; A[1028 * 256 + rr] = 0;
        }
    } else {
        // v in [657, 721): zero A1 for layer 0's atomic accumulation
        int b = v - 657;
        size_t base = (size_t)b * 4096 + tid * 4;
        float4 z4 = {0.f, 0.f, 0.f, 0.f};
#pragma unroll
        for (int r = 0; r < 4; ++r) *(float4*)&A1[base + r * 1024] = z4;
    }
}

// ---------------- D2 = max(sq_i + sq_j - 2 Z^T Z, 0); sum(D2) -> sig ----------------
__global__ __launch_bounds__(256) void k_d2(const float* __restrict__ Zc,
                                            float* __restrict__ D2, float* __restrict__ sig) {
    __shared__ __align__(16) float Zi[32 * 36];
    __shared__ __align__(16) float Zj[32 * 68];
    __shared__ float sqi[32], sqj[64];
    __shared__ float red[4];
    const int tid = threadIdx.x;
    const int tx = tid & 15, ty = tid >> 4;
    const int j0 = blockIdx.x * 64, i0 = blockIdx.y * 32;
    if (tid < 32) sqi[tid] = 0.f;
    else if (tid < 96) sqj[tid - 32] = 0.f;
    float acc[2][4] = {};
    for (int c0 = 0; c0 < NOPEN; c0 += 32) {
        for (int idx = tid; idx < 32 * 32; idx += 256) {
            int c = idx >> 5, ii = idx & 31;
            Zi[c * 36 + ii] = Zc[(c0 + c) * NN + i0 + ii];
        }
        for (int idx = tid; idx < 32 * 64; idx += 256) {
            int c = idx >> 6, jj = idx & 63;
            Zj[c * 68 + jj] = Zc[(c0 + c) * NN + j0 + jj];
        }
        __syncthreads();
        if (tid < 32) {
            float s = 0.f;
            for (int c = 0; c < 32; ++c) { float x = Zi[c * 36 + tid]; s = fmaf(x, x, s); }
            sqi[tid] += s;
        } else if (tid < 96) {
            int jj = tid - 32;
            float s = 0.f;
            for (int c = 0; c < 32; ++c) { float x = Zj[c * 68 + jj]; s = fmaf(x, x, s); }
            sqj[jj] += s;
        }
#pragma unroll 8
        for (int c = 0; c < 32; ++c) {
            float2 zi = *(const float2*)&Zi[c * 36 + ty * 2];
            float4 zj = *(const float4*)&Zj[c * 68 + tx * 4];
            acc[0][0] = fmaf(zi.x, zj.x, acc[0][0]);
            acc[0][1] = fmaf(zi.x, zj.y, acc[0][1]);
            acc[0][2] = fmaf(zi.x, zj.z, acc[0][2]);
            acc[0][3] = fmaf(zi.x, zj.w, acc[0][3]);
            acc[1][0] = fmaf(zi.y, zj.x, acc[1][0]);
            acc[1][1] = fmaf(zi.y, zj.y, acc[1][1]);
            acc[1][2] = fmaf(zi.y, zj.z, acc[1][2]);
            acc[1][3] = fmaf(zi.y, zj.w, acc[1][3]);
        }
        __syncthreads();
    }
    float part = 0.f;
#pragma unroll
    for (int m = 0; m < 2; ++m) {
        int i = i0 + ty * 2 + m;
        float sqi_v = sqi[ty * 2 + m];
        float4 d;
        d.x = fmaxf(sqi_v + sqj[tx * 4 + 0] - 2.f * acc[m][0], 0.f);
        d.y = fmaxf(sqi_v + sqj[tx * 4 + 1] - 2.f * acc[m][1], 0.f);
        d.z = fmaxf(sqi_v + sqj[tx * 4 + 2] - 2.f * acc[m][2], 0.f);
        d.w = fmaxf(sqi_v + sqj[tx * 4 + 3] - 2.f * acc[m][3], 0.f);
        *(float4*)&D2[(size_t)i * NN + j0 + tx * 4] = d;
        part += (d.x + d.y) + (d.z + d.w);
    }
#pragma unroll
    for (int off = 32; off > 0; off >>= 1) part += __shfl_down(part, off);
    if ((tid & 63) == 0) red[tid >> 6] = part;
    __syncthreads();
    if (tid == 0) atomicAdd(sig, red[0] + red[1] + red[2] + red[3]);
}

// ---------------- deg_i = sum_j exp(-D2_ij/sigma); Dh_i = rsqrt(deg_i) ----------------
__global__ void k_deg(const float* __restrict__ D2, const float* __restrict__ sig,
                      float* __restrict__ Dh) {
    __shared__ float red[4];
    int i = blockIdx.x, tid = threadIdx.x;
    float inv = 1.f / (sig[0] * (1.f / 1048576.f) + 1e-12f);
    float4 v = *(const float4*)&D2[(size_t)i * NN + tid * 4];
    float s = __expf(-v.x * inv) + __expf(-v.y * inv) + __expf(-v.z * inv) + __expf(-v.w * inv);
#pragma unroll
    for (int off = 32; off > 0; off >>= 1) s += __shfl_down(s, off);
    if ((tid & 63) == 0) red[tid >> 6] = s;
    __syncthreads();
    if (tid == 0) Dh[i] = rsqrtf(red[0] + red[1] + red[2] + red[3]);
}

// ---------------- Lb_ij = bf16( delta_ij - Dh_i Dh_j exp(-D2_ij/sigma) ) ----------------
__global__ void k_L(const float* __restrict__ D2, const float* __restrict__ sig,
                    const float* __restrict__ Dh, ushort* __restrict__ Lb) {
    int i = blockIdx.x, tid = threadIdx.x;
    int j = tid * 4;
    float inv = 1.f / (sig[0] * (1.f / 1048576.f) + 1e-12f);
    float dhi = Dh[i];
    float4 v = *(const float4*)&D2[(size_t)i * NN + j];
    float4 dj = *(const float4*)&Dh[j];
    float4 o;
    o.x = -dhi * dj.x * __expf(-v.x * inv);
    o.y = -dhi * dj.y * __expf(-v.y * inv);
    o.z = -dhi * dj.z * __expf(-v.z * inv);
    o.w = -dhi * dj.w * __expf(-v.w * inv);
    if (i == j + 0) o.x += 1.f;
    if (i == j + 1) o.y += 1.f;
    if (i == j + 2) o.z += 1.f;
    if (i == j + 3) o.w += 1.f;
    ushort4 ob; ob.x = f2bf(o.x); ob.y = f2bf(o.y); ob.z = f2bf(o.z); ob.w = f2bf(o.w);
    *(ushort4*)&Lb[(size_t)i * NN + j] = ob;
}

// ---------------- MFMA conv1d: C[co,p] = sum_{t,ci} W[t][co][ci] * Zct[p+t][ci] ----------------
// grid (32 p, 8 co, 2 z); block tile 32co x 32p; 2 blocks/CU for latency hiding
__global__ __launch_bounds__(256) void k_conv(const ushort* __restrict__ Zct,
        const ushort* __restrict__ Wf1, float* __restrict__ C0, ushort* __restrict__ C1b) {
    const int z = blockIdx.z;
    const int p0 = blockIdx.x * 32, co0 = blockIdx.y * 32;
    __shared__ ushort Xs[40 * 136];
    const int tid = threadIdx.x;
    const ushort* Zz = Zct + z * (1032 * 128);
    for (int idx = tid; idx < 640; idx += 256) {
        int row = idx >> 4, ch = (idx & 15) * 8;
        *(bfrag*)&Xs[row * 136 + ch] = *(const bfrag*)&Zz[(p0 + row) * 128 + ch];
    }
    __syncthreads();
    const int l = tid & 63, wv = tid >> 6;
    const int wm = wv >> 1, wn = wv & 1;
    const int lm = l & 15, lq = l >> 4;
    const ushort* wf = Wf1 + (((size_t)z * 144 + (blockIdx.y * 2 + wm)) << 11) + l * 8;
    floatx4 acc = {};
    bfrag a_cur[4];
#pragma unroll
    for (int kc = 0; kc < 4; ++kc) a_cur[kc] = *(const bfrag*)(wf + (kc << 9));
    for (int t = 0; t < 9; ++t) {
        bfrag a_nxt[4];
        if (t < 8) {
            const ushort* wptr = wf + (size_t)(t + 1) * (16 << 11);
#pragma unroll
            for (int kc = 0; kc < 4; ++kc) a_nxt[kc] = *(const bfrag*)(wptr + (kc << 9));
        }
        const int xbase = (wn * 16 + lm + t) * 136 + lq * 8;
#pragma unroll
        for (int kc = 0; kc < 4; ++kc) {
            bfrag b0 = *(const bfrag*)&Xs[xbase + kc * 32];
            acc = __builtin_amdgcn_mfma_f32_16x16x32_bf16(a_cur[kc], b0, acc, 0, 0, 0);
        }
#pragma unroll
        for (int kc = 0; kc < 4; ++kc) a_cur[kc] = a_nxt[kc];
    }
    const int cog = co0 + wm * 16 + lq * 4;
    const int pg = p0 + wn * 16 + lm;
#pragma unroll
    for (int r = 0; r < 4; ++r) {
        if (z == 0) C0[(cog + r) * NN + pg] = acc[r];
        else        C1b[(cog + r) * NN + pg] = f2bf(acc[r]);
    }
}

// ---------------- MFMA split-K GEMM with atomic accumulate: Out += X[:, kc:kc+128] @ L[kc:kc+128, :] ----------------
// grid (16 nt of 64, M/64 mt, 8 ksp); Out zeroed (A1) or pre-seeded (Tacc) beforehand
__global__ __launch_bounds__(256) void k_xl_mfma(const ushort* __restrict__ X,
                                                 const ushort* __restrict__ Lb,
                                                 float* __restrict__ Out) {
    __shared__ __align__(16) ushort As[64 * 136];
    __shared__ __align__(16) ushort Bs[64 * 136];
    const int tid = threadIdx.x;
    const int lane = tid & 63, wave = tid >> 6;
    const int wm = wave >> 1, wn = wave & 1;
    const int n0 = blockIdx.x * 64, m0 = blockIdx.y * 64, kc = blockIdx.z * 128;
    {
        int q = tid;
#pragma unroll
        for (int r = 0; r < 4; ++r, q += 256) {
            int row = q >> 4, ch = (q & 15) * 8;
            *(bfrag*)&As[row * 136 + ch] = *(const bfrag*)&X[(m0 + row) * NN + kc + ch];
        }
        q = tid;
#pragma unroll
        for (int r = 0; r < 4; ++r, q += 256) {
            int row = q >> 4, ch = (q & 15) * 8;
            *(bfrag*)&Bs[row * 136 + ch] = *(const bfrag*)&Lb[(n0 + row) * NN + kc + ch];
        }
    }
    __syncthreads();
    floatx4 acc[2][2] = {};
    const int lrow = (lane & 15) * 136;
    const int koff = (lane >> 4) * 8;
#pragma unroll
    for (int ks = 0; ks < 4; ++ks) {
        bfrag a[2], b[2];
#pragma unroll
        for (int i = 0; i < 2; ++i)
            a[i] = *(const bfrag*)&As[(wm * 32 + i * 16) * 136 + lrow + ks * 32 + koff];
#pragma unroll
        for (int j = 0; j < 2; ++j)
            b[j] = *(const bfrag*)&Bs[(wn * 32 + j * 16) * 136 + lrow + ks * 32 + koff];
#pragma unroll
        for (int i = 0; i < 2; ++i)
#pragma unroll
            for (int j = 0; j < 2; ++j)
                acc[i][j] = __builtin_amdgcn_mfma_f32_16x16x32_bf16(a[i], b[j], acc[i][j], 0, 0, 0);
    }
    const int mg0 = m0 + wm * 32 + (lane >> 4) * 4;
    const int ng0 = n0 + wn * 32 + (lane & 15);
#pragma unroll
    for (int i = 0; i < 2; ++i)
#pragma unroll
        for (int j = 0; j < 2; ++j)
#pragma unroll
            for (int r = 0; r < 4; ++r)
                atomicAdd(&Out[(size_t)(mg0 + i * 16 + r) * NN + ng0 + j * 16], acc[i][j][r]);
}

// ---------------- instance norm stats over C0 (arr=0) / A1 (arr=1) ----------------
// grid (NHID, 2), one channel per block
__global__ void k_inorm(const float* __restrict__ C0, const float* __restrict__ A1,
                        float* __restrict__ Mu, float* __restrict__ Rs) {
    const int c = blockIdx.x, arr = blockIdx.y, tid = threadIdx.x;
    __shared__ float rs[4], rq[4];
    const float* in = arr ? A1 : C0;
    float4 v = *(const float4*)&in[c * NN + tid * 4];
    float s = (v.x + v.y) + (v.z + v.w);
    float q = (v.x * v.x + v.y * v.y) + (v.z * v.z + v.w * v.w);
#pragma unroll
    for (int off = 32; off > 0; off >>= 1) { s += __shfl_down(s, off); q += __shfl_down(q, off); }
    if ((tid & 63) == 0) { rs[tid >> 6] = s; rq[tid >> 6] = q; }
    __syncthreads();
    if (tid == 0) {
        float S = rs[0] + rs[1] + rs[2] + rs[3];
        float Q = rq[0] + rq[1] + rq[2] + rq[3];
        float mean = S * (1.f / NN);
        float var = Q * (1.f / NN) - mean * mean;
        Mu[arr * NHID + c] = mean;
        Rs[arr * NHID + c] = rsqrtf(var + IN_EPS);
    }
}

// ---------------- normalize + relu + bf16 + transpose -> At[pos+4][co] ----------------
// grid (32 p, 4 co64, 2 arr)
__global__ __launch_bounds__(256) void k_normT(const float* __restrict__ C0,
        const float* __restrict__ A1, const float* __restrict__ Mu, const float* __restrict__ Rs,
        ushort* __restrict__ At0, ushort* __restrict__ At1) {
    const int arr = blockIdx.z;
    const int p0 = blockIdx.x * 32, co0 = blockIdx.y * 64;
    const float* in = arr ? A1 : C0;
    ushort* out = arr ? At1 : At0;
    __shared__ ushort Ls[32 * 72];
    const int tid = threadIdx.x;
#pragma unroll
    for (int r = 0; r < 2; ++r) {
        int idx = r * 256 + tid;      // 64 co x 8 p-chunks(4)
        int col = idx >> 3, pq = idx & 7;
        int co = co0 + col;
        float4 v = *(const float4*)&in[(size_t)co * NN + p0 + pq * 4];
        float m = Mu[arr * NHID + co], sc = Rs[arr * NHID + co];
        Ls[(pq * 4 + 0) * 72 + col] = f2bf(fmaxf((v.x - m) * sc, 0.f));
        Ls[(pq * 4 + 1) * 72 + col] = f2bf(fmaxf((v.y - m) * sc, 0.f));
        Ls[(pq * 4 + 2) * 72 + col] = f2bf(fmaxf((v.z - m) * sc, 0.f));
        Ls[(pq * 4 + 3) * 72 + col] = f2bf(fmaxf((v.w - m) * sc, 0.f));
    }
    __syncthreads();
    {
        int row = tid >> 3, ch = (tid & 7) * 8;   // 32 rows x 8 chunks(8)
        *(bfrag*)&out[(size_t)(p0 + row + 4) * 256 + co0 + ch] = *(const bfrag*)&Ls[row * 72 + ch];
    }
}

// ---------------- MFMA convT: T[ci,p] = sum_{t,co} W[t][ci][co] * At[p+8-t][co] ----------------
// grid (32 p, 8 ci16, 2 z); block tile 16ci x 32p; 2 waves on p-halves x 2 waves on k-halves + LDS reduce
__global__ __launch_bounds__(256) void k_convT(const ushort* __restrict__ At0,
        const ushort* __restrict__ At1, const ushort* __restrict__ Wf2,
        float* __restrict__ Tacc, ushort* __restrict__ T1b) {
    const int z = blockIdx.z;
    const int p0 = blockIdx.x * 32, ci0 = blockIdx.y * 16;
    __shared__ ushort Al[40 * 264];
    __shared__ float Red[2][64][4];
    const ushort* A = z ? At1 : At0;
    const int tid = threadIdx.x;
    for (int idx = tid; idx < 1280; idx += 256) {
        int row = idx >> 5, ch = (idx & 31) * 8;
        *(bfrag*)&Al[row * 264 + ch] = *(const bfrag*)&A[(p0 + row) * 256 + ch];
    }
    __syncthreads();
    const int l = tid & 63, wv = tid >> 6;
    const int ph = wv & 1, kh = wv >> 1;   // p-half, k-half
    const int lm = l & 15, lq = l >> 4;
    const ushort* wbase = Wf2 + (((size_t)z * 72 + blockIdx.y) << 12) + ((kh * 4) << 9) + l * 8;
    floatx4 acc0 = {}, acc1 = {};
    bfrag a_cur[4];
#pragma unroll
    for (int jj = 0; jj < 4; ++jj) a_cur[jj] = *(const bfrag*)(wbase + (jj << 9));
    for (int t = 0; t < 9; ++t) {
        bfrag a_nxt[4];
        if (t < 8) {
            const ushort* wptr = wbase + (size_t)(t + 1) * (8 << 12);
#pragma unroll
            for (int jj = 0; jj < 4; ++jj) a_nxt[jj] = *(const bfrag*)(wptr + (jj << 9));
        }
        const int abase = (ph * 16 + lm + 8 - t) * 264 + lq * 8;
#pragma unroll
        for (int jj = 0; jj < 4; jj += 2) {
            bfrag b0 = *(const bfrag*)&Al[abase + (kh * 4 + jj) * 32];
            acc0 = __builtin_amdgcn_mfma_f32_16x16x32_bf16(a_cur[jj], b0, acc0, 0, 0, 0);
            bfrag b1 = *(const bfrag*)&Al[abase + (kh * 4 + jj + 1) * 32];
            acc1 = __builtin_amdgcn_mfma_f32_16x16x32_bf16(a_cur[jj + 1], b1, acc1, 0, 0, 0);
        }
#pragma unroll
        for (int jj = 0; jj < 4; ++jj) a_cur[jj] = a_nxt[jj];
    }
    floatx4 acc = acc0 + acc1;
    __syncthreads();
    if (kh == 1) {
#pragma unroll
        for (int r = 0; r < 4; ++r) Red[ph][l][r] = acc[r];
    }
    __syncthreads();
    if (kh == 0) {
#pragma unroll
        for (int r = 0; r < 4; ++r) acc[r] += Red[ph][l][r];
        const int cig = ci0 + lq * 4;
        const int pg = p0 + ph * 16 + lm;
#pragma unroll
        for (int r = 0; r < 4; ++r) {
            if (z == 0) Tacc[(cig + r) * NN + pg] = acc[r];
            else        T1b[(cig + r) * NN + pg] = f2bf(acc[r]);
        }
    }
}

// ---------------- leapfrog (Tacc already = convT + XL2 via atomics) + next Zct + prepw + sig=0 + A1=0 ----------------
// grid 337: v<128 leap; 128..271 prepw(lnext) if doprep; v=272 zero sig; 273..336 zero A1
__global__ __launch_bounds__(256) void k_leap(const float* __restrict__ Tacc,
        const float* __restrict__ Zc, float* __restrict__ Zo,
        const float* __restrict__ BiasN, ushort* __restrict__ Zct,
        const float* __restrict__ W, ushort* __restrict__ Wf1, ushort* __restrict__ Wf2,
        float* __restrict__ A1, float* __restrict__ sig, int lnext, int doprep) {
    const int v = blockIdx.x, tid = threadIdx.x;
    if (v < 128) {
        int off = (v * 256 + tid) * 4;
        float4 a = *(const float4*)&Tacc[off];
        float4 zc = *(const float4*)&Zc[off];
        float4 zo = *(const float4*)&Zo[off];
        float4 zn;
        zn.x = 2.f * zc.x - zo.x - H2 * a.x;
        zn.y = 2.f * zc.y - zo.y - H2 * a.y;
        zn.z = 2.f * zc.z - zo.z - H2 * a.z;
        zn.w = 2.f * zc.w - zo.w - H2 * a.w;
        *(float4*)&Zo[off] = zn;
        int ci = off >> 10, n = off & 1023;
#pragma unroll
        for (int z = 0; z < 2; ++z) {
            float bz = BiasN[z * NOPEN + ci];
            ushort* Zz = Zct + z * (1032 * 128);
            Zz[(n + 4) * 128 + ci] = f2bf(zn.x + bz);
            Zz[(n + 5) * 128 + ci] = f2bf(zn.y + bz);
            Zz[(n + 6) * 128 + ci] = f2bf(zn.z + bz);
            Zz[(n + 7) * 128 + ci] = f2bf(zn.w + bz);
        }
    } else if (v < 272) {
        if (doprep) prepw_piece(W, Wf1, Wf2, v - 128, lnext, tid);
    } else if (v == 272) {
        if (tid == 0) sig[0] = 0.f;
    } else {
        // v in [273, 337): zero A1 for next layer's atomic accumulation
        int b = v - 273;
        size_t base = (size_t)b * 4096 + tid * 4;
        float4 z4 = {0.f, 0.f, 0.f, 0.f};
#pragma unroll
        for (int r = 0; r < 4; ++r) *(float4*)&A1[base + r * 1024] = z4;
    }
}

// ---------------- closing: out = concat(Kclose @ Zc, Kclose @ Zold) ----------------
__global__ void k_close(const float* __restrict__ Kclose, const float* __restrict__ Zc,
                        const float* __restrict__ Zold, float* __restrict__ out) {
    int n = blockIdx.x * 256 + threadIdx.x;
    int o = blockIdx.y;
    const float* Zb = blockIdx.z ? Zold : Zc;
    float a = 0.f;
#pragma unroll
    for (int c = 0; c < NOPEN; ++c) a = fmaf(Kclose[o * NOPEN + c], Zb[c * NN + n], a);
    out[blockIdx.z * (NCLOSE * NN) + o * NN + n] = a;
}

extern "C" void kernel_launch(void* const* d_in, const int* in_sizes, int n_in,
                              void* d_out, int out_size, void* d_ws, size_t ws_size,
                              hipStream_t stream) {
    const float* Z      = (const float*)d_in[0];
    const float* Kopen  = (const float*)d_in[1];
    const float* Kclose = (const float*)d_in[2];
    const float* W      = (const float*)d_in[3];
    const float* Bias   = (const float*)d_in[4];
    float* out = (float*)d_out;
    float* ws  = (float*)d_ws;

    // workspace layout (float units)
    float* Zb0   = ws + 0;         // 131072
    float* Zb1   = ws + 131072;    // 131072
    float* D2    = ws + 262144;    // 1048576
    float* C0    = ws + 1310720;   // 262144
    float* A1    = ws + 1572864;   // 262144
    float* Tacc  = ws + 1835008;   // 131072
    float* Dh    = ws + 5111808;   // 1024
    float* sig   = ws + 5112832;   // 1024
    float* Mu    = ws + 5113856;   // 1024 (512 used)
    float* Rs    = ws + 5114880;   // 1024
    ushort* Lb  = (ushort*)(ws + 5115904); // 1024*1024 us
    ushort* C1b = (ushort*)(ws + 5640192); // 256*1024 us
    ushort* T1b = (ushort*)(ws + 5771264); // 128*1024 us
    ushort* Zct = (ushort*)(ws + 5836800); // 2*1032*128 us
    ushort* At0 = (ushort*)(ws + 5968896); // 1032*256 us
    ushort* At1 = (ushort*)(ws + 6100992); // 1032*256 us
    ushort* Wf1 = (ushort*)(ws + 6233088); // 2*9*16*4*512 us (conv frags)
    ushort* Wf2 = (ushort*)(ws + 6528000); // 2*9*8*8*512 us  (convT frags)

    k_open<<<dim3(721), 256, 0, stream>>>(Kopen, Z, Zb0, Zb1, Bias, Zct, At0, At1,
                                          W, Wf1, Wf2, sig, A1);

    float* Zc = Zb0;
    float* Zold = Zb1;
    for (int i = 0; i < NLAYERS; ++i) {
        if (i % 10 == 0) {
            k_d2<<<dim3(16, 32), 256, 0, stream>>>(Zc, D2, sig);
            k_deg<<<dim3(NN), 256, 0, stream>>>(D2, sig, Dh);
            k_L<<<dim3(NN), 256, 0, stream>>>(D2, sig, Dh, Lb);
        }
        k_conv<<<dim3(32, 8, 2), 256, 0, stream>>>(Zct, Wf1, C0, C1b);
        k_xl_mfma<<<dim3(16, 4, 8), 256, 0, stream>>>(C1b, Lb, A1);    // XL1 -> A1 (zeroed)
        k_inorm<<<dim3(NHID, 2), 256, 0, stream>>>(C0, A1, Mu, Rs);
        k_normT<<<dim3(32, 4, 2), 256, 0, stream>>>(C0, A1, Mu, Rs, At0, At1);
        k_convT<<<dim3(32, 8, 2), 256, 0, stream>>>(At0, At1, Wf2, Tacc, T1b);
        k_xl_mfma<<<dim3(16, 2, 8), 256, 0, stream>>>(T1b, Lb, Tacc);  // XL2 += into Tacc
        int lnext = (i + 1 < NLAYERS) ? i + 1 : NLAYERS - 1;
        k_leap<<<dim3(337), 256, 0, stream>>>(Tacc, Zc, Zold,
                                              Bias + (size_t)lnext * 2 * NOPEN, Zct,
                                              W, Wf1, Wf2, A1, sig, lnext,
                                              (i + 1 < NLAYERS) ? 1 : 0);
        float* tmp = Zc; Zc = Zold; Zold = tmp;
    }

    k_close<<<dim3(4, NCLOSE, 2), 256, 0, stream>>>(Kclose, Zc, Zold, out);
}